// Round 12
// baseline (2911.502 us; speedup 1.0000x reference)
//
#include <hip/hip_runtime.h>

#define B_ 16
#define S_ 4096
#define D_ 256
#define H_ 256

typedef _Float16 h8v __attribute__((ext_vector_type(8)));
typedef float f4 __attribute__((ext_vector_type(4)));

// LDS-only barrier: drain LDS ops, NOT vmcnt (T4) — the out-buffer store
// (slot t) and prefetch load (slot t+4) never alias within the window.
static __device__ __forceinline__ void lds_barrier() {
    asm volatile("s_waitcnt lgkmcnt(0)" ::: "memory");
    __builtin_amdgcn_s_barrier();
}

// Kernel 1: xp[row][h] = sum_d x[row][d] * Wx[d][h] + bias[h], into d_out.
__global__ __launch_bounds__(256) void xproj_kernel(
    const float* __restrict__ x, const float* __restrict__ Wx,
    const float* __restrict__ bias, float* __restrict__ out)
{
    __shared__ float xs[32 * 256];
    const int tid = threadIdx.x;
    const long long row0 = (long long)blockIdx.x * 32;

    {
        const f4* __restrict__ xg = (const f4*)(x + row0 * D_);
        f4* xsv = (f4*)xs;
        #pragma unroll
        for (int k = 0; k < 8; ++k)
            xsv[tid + k * 256] = xg[tid + k * 256];
    }
    __syncthreads();

    const int j = tid;
    float acc[32];
    const float bj = bias[j];
    #pragma unroll
    for (int r = 0; r < 32; ++r) acc[r] = bj;

    for (int d4 = 0; d4 < D_ / 4; ++d4) {
        const float w0 = Wx[(d4 * 4 + 0) * H_ + j];
        const float w1 = Wx[(d4 * 4 + 1) * H_ + j];
        const float w2 = Wx[(d4 * 4 + 2) * H_ + j];
        const float w3 = Wx[(d4 * 4 + 3) * H_ + j];
        #pragma unroll
        for (int r = 0; r < 32; ++r) {
            f4 xv = *(const f4*)&xs[r * 256 + d4 * 4];
            acc[r] = fmaf(xv.x, w0, acc[r]);
            acc[r] = fmaf(xv.y, w1, acc[r]);
            acc[r] = fmaf(xv.z, w2, acc[r]);
            acc[r] = fmaf(xv.w, w3, acc[r]);
        }
    }
    #pragma unroll
    for (int r = 0; r < 32; ++r)
        out[(row0 + r) * H_ + j] = acc[r];
}

// Kernel 2: MFMA scan, TWO independent batches per block (8 blocks, 512
// threads). Waves 0-3 -> batch 2*blk, waves 4-7 -> batch 2*blk+1. Each
// 4-wave group runs the round-11 replicated-row MFMA matvec; the two
// groups share the CU, so one group's MFMA issue hides the other's
// ds_read/MFMA-chain latency (2 waves/SIMD from independent recurrences).
// af is a reloaded half-buffer (4 frags) to stay under 256 unified regs
// per wave (2 waves/SIMD residency). One lgkm-only barrier per step.
__global__ __launch_bounds__(512, 1) void scan_kernel(
    const float* __restrict__ Wh, const float* __restrict__ state0,
    float* __restrict__ out)
{
    __shared__ __align__(16) _Float16 h_lds[2][2][H_];   // [batch-half][buf][j]
    const int tid = threadIdx.x;
    const int l   = tid & 63;
    const int wav = tid >> 6;        // 0..7
    const int wb  = wav >> 2;        // batch half within block
    const int wq  = wav & 3;         // wave within the batch group
    const int lc  = l & 15;
    const int kg  = l >> 4;          // 0..3
    const int b   = blockIdx.x * 2 + wb;
    const int j_own = 64 * wq + 16 * kg + lc;   // bijection per batch group

    // B-frags: lane holds Wh[k][j], j = 64wq+16nt+lc, k = 32ks+8kg+e
    // (same (kg,e)->k map as A: permutation-safe, verified round 7/11).
    h8v bf[4][8];
    #pragma unroll
    for (int nt = 0; nt < 4; ++nt) {
        const int j = 64 * wq + 16 * nt + lc;
        #pragma unroll
        for (int ks = 0; ks < 8; ++ks) {
            #pragma unroll
            for (int e = 0; e < 8; ++e) {
                const int k = 32 * ks + 8 * kg + e;
                bf[nt][ks][e] = (_Float16)Wh[k * H_ + j];
            }
        }
    }

    h_lds[wb][0][j_own] = (_Float16)state0[b * H_ + j_own];

    float* __restrict__ outb = out + (long long)b * S_ * H_;

    // xp prefetch ring, distance 4 (static indices via unroll-4)
    float xr[4];
    #pragma unroll
    for (int k = 0; k < 4; ++k)
        xr[k] = outb[(long long)k * H_ + j_own];
    __syncthreads();

    const int abase = 8 * kg;   // lane's A-slice offset within a ks block

    #pragma unroll 4
    for (int st = 0; st < S_; ++st) {
        const int p = st & 1;
        const _Float16* hb = h_lds[wb][p];

        f4 acc0 = {0.f, 0.f, 0.f, 0.f};
        f4 acc1 = {0.f, 0.f, 0.f, 0.f};
        f4 acc2 = {0.f, 0.f, 0.f, 0.f};
        f4 acc3 = {0.f, 0.f, 0.f, 0.f};

        // half 1: ks 0..3 (af half-buffer keeps regs <= 256/wave)
        h8v af[4];
        #pragma unroll
        for (int ks = 0; ks < 4; ++ks)
            af[ks] = *(const h8v*)&hb[32 * ks + abase];
        #pragma unroll
        for (int ks = 0; ks < 4; ++ks) {
            acc0 = __builtin_amdgcn_mfma_f32_16x16x32_f16(af[ks], bf[0][ks], acc0, 0, 0, 0);
            acc1 = __builtin_amdgcn_mfma_f32_16x16x32_f16(af[ks], bf[1][ks], acc1, 0, 0, 0);
            acc2 = __builtin_amdgcn_mfma_f32_16x16x32_f16(af[ks], bf[2][ks], acc2, 0, 0, 0);
            acc3 = __builtin_amdgcn_mfma_f32_16x16x32_f16(af[ks], bf[3][ks], acc3, 0, 0, 0);
        }
        // half 2: ks 4..7
        #pragma unroll
        for (int ks = 0; ks < 4; ++ks)
            af[ks] = *(const h8v*)&hb[32 * (4 + ks) + abase];
        #pragma unroll
        for (int ks = 0; ks < 4; ++ks) {
            acc0 = __builtin_amdgcn_mfma_f32_16x16x32_f16(af[ks], bf[0][4 + ks], acc0, 0, 0, 0);
            acc1 = __builtin_amdgcn_mfma_f32_16x16x32_f16(af[ks], bf[1][4 + ks], acc1, 0, 0, 0);
            acc2 = __builtin_amdgcn_mfma_f32_16x16x32_f16(af[ks], bf[2][4 + ks], acc2, 0, 0, 0);
            acc3 = __builtin_amdgcn_mfma_f32_16x16x32_f16(af[ks], bf[3][4 + ks], acc3, 0, 0, 0);
        }

        // replicated A => all C rows equal; pick nt == kg (3 cndmask)
        float v = acc0[0];
        v = (kg == 1) ? acc1[0] : v;
        v = (kg == 2) ? acc2[0] : v;
        v = (kg == 3) ? acc3[0] : v;

        const float pre = v + xr[st & 3];
        const float e = __builtin_amdgcn_exp2f(pre * 2.8853900817779268f);
        const float hn = fmaf(-2.f, __builtin_amdgcn_rcpf(e + 1.f), 1.f);

        outb[(long long)st * H_ + j_own] = hn;    // stays in flight (no vmcnt drain)
        h_lds[wb][p ^ 1][j_own] = (_Float16)hn;   // publish h for t+1

        const int nt4 = st + 4;
        xr[st & 3] = (nt4 < S_) ? outb[(long long)nt4 * H_ + j_own] : 0.f;
        lds_barrier();
    }
}

extern "C" void kernel_launch(void* const* d_in, const int* in_sizes, int n_in,
                              void* d_out, int out_size, void* d_ws, size_t ws_size,
                              hipStream_t stream) {
    const float* x  = (const float*)d_in[0];   // [B,S,D]
    const float* s0 = (const float*)d_in[1];   // [B,H]
    const float* Wx = (const float*)d_in[2];   // [D,H]
    const float* Wh = (const float*)d_in[3];   // [H,H]
    const float* bv = (const float*)d_in[4];   // [H]
    float* out = (float*)d_out;                // [B,S,H]

    xproj_kernel<<<dim3((B_ * S_) / 32), dim3(256), 0, stream>>>(x, Wx, bv, out);
    scan_kernel<<<dim3(B_ / 2), dim3(512), 0, stream>>>(Wh, s0, out);
}